// Round 1
// baseline (377.013 us; speedup 1.0000x reference)
//
#include <hip/hip_runtime.h>
#include <math.h>

// ---------------------------------------------------------------------------
// GraphConvolution: B=2, N=50000, D=64, E=800000, H=32 (derived from in_sizes)
// Pipeline:
//   k_node : tf_feat = x_infl @ W; per-node dots (s_r,s_c,e_r,e_c); gate MLP;
//            pack node4[b][n] = {e_c, s_c, x_state, gate}
//   k_hist/k_scan1/2/3/k_fill : build CSR (row -> col list), no sorting needed
//   k_row  : one wave per (b,row); online-softmax attention aggregation +
//            state segment-sum + both output epilogues. No float atomics.
// ---------------------------------------------------------------------------

__device__ __forceinline__ float elu_f(float x) {
    return x > 0.f ? x : __expf(x) - 1.f;
}

__device__ __forceinline__ float4 wsum4(float4 v) {
#pragma unroll
    for (int m = 1; m < 64; m <<= 1) {
        v.x += __shfl_xor(v.x, m, 64);
        v.y += __shfl_xor(v.y, m, 64);
        v.z += __shfl_xor(v.z, m, 64);
        v.w += __shfl_xor(v.w, m, 64);
    }
    return v;
}

// --- per-node transform: 4 waves/block, 4 rows/wave (amortize W LDS reads) ---
__global__ __launch_bounds__(256) void k_node(
    const float* __restrict__ x_state, const float* __restrict__ x_infl,
    const float* __restrict__ Wg, const float* __restrict__ sbeta,
    const float* __restrict__ w1, const float* __restrict__ b1,
    const float* __restrict__ w2, const float* __restrict__ b2,
    const float* __restrict__ iatt,
    float* __restrict__ tf, float4* __restrict__ node4,
    float* __restrict__ er_arr, float* __restrict__ sr_arr, int BN)
{
    __shared__ float Ws[4096];         // W[k][j] at k*64+j (2-way bank alias: free)
    __shared__ float4 xT[4][64];       // per wave: column-k of its 4 rows
    __shared__ float mw1[32], mb1[32], mw2[32];
    __shared__ float mb2s;

    int tid = threadIdx.x;
#pragma unroll
    for (int i = tid; i < 4096; i += 256) Ws[i] = Wg[i];
    if (tid < 32) { mw1[tid] = w1[tid]; mb1[tid] = b1[tid]; mw2[tid] = w2[tid]; }
    if (tid == 0) mb2s = b2[0];

    int lane = tid & 63, w = tid >> 6;
    int rbase = blockIdx.x * 16 + w * 4;

    float xv0 = x_infl[(size_t)(rbase + 0) * 64 + lane];
    float xv1 = x_infl[(size_t)(rbase + 1) * 64 + lane];
    float xv2 = x_infl[(size_t)(rbase + 2) * 64 + lane];
    float xv3 = x_infl[(size_t)(rbase + 3) * 64 + lane];
    xT[w][lane] = make_float4(xv0, xv1, xv2, xv3);
    __syncthreads();

    float a0 = 0.f, a1 = 0.f, a2 = 0.f, a3 = 0.f;
#pragma unroll 16
    for (int k = 0; k < 64; ++k) {
        float wv = Ws[k * 64 + lane];
        float4 xk = xT[w][k];
        a0 = fmaf(xk.x, wv, a0);
        a1 = fmaf(xk.y, wv, a1);
        a2 = fmaf(xk.z, wv, a2);
        a3 = fmaf(xk.w, wv, a3);
    }
    tf[(size_t)(rbase + 0) * 64 + lane] = a0;
    tf[(size_t)(rbase + 1) * 64 + lane] = a1;
    tf[(size_t)(rbase + 2) * 64 + lane] = a2;
    tf[(size_t)(rbase + 3) * 64 + lane] = a3;

    float bsr = sbeta[lane], bsc = sbeta[64 + lane];
    float ber = iatt[lane],  bec = iatt[64 + lane];
    float4 d0 = wsum4(make_float4(a0 * bsr, a0 * bsc, a0 * ber, a0 * bec));
    float4 d1 = wsum4(make_float4(a1 * bsr, a1 * bsc, a1 * ber, a1 * bec));
    float4 d2 = wsum4(make_float4(a2 * bsr, a2 * bsc, a2 * ber, a2 * bec));
    float4 d3 = wsum4(make_float4(a3 * bsr, a3 * bsc, a3 * ber, a3 * bec));

    if (lane < 4) {
        float4 dd = (lane == 0) ? d0 : (lane == 1) ? d1 : (lane == 2) ? d2 : d3;
        int rr = rbase + lane;
        float xs = x_state[rr];
        float t = 0.f;
#pragma unroll
        for (int h = 0; h < 32; ++h) {
            float u = fmaf(xs, mw1[h], mb1[h]);
            u = elu_f(u);
            t = fmaf(u, mw2[h], t);
        }
        float gate = elu_f(t + mb2s);
        node4[rr] = make_float4(dd.w /*e_c*/, dd.y /*s_c*/, xs, gate);
        er_arr[rr] = dd.z;  // e_r
        sr_arr[rr] = dd.x;  // s_r
    }
}

// --- CSR build ---
__global__ __launch_bounds__(256) void k_hist(const int2* __restrict__ Li,
                                              int* __restrict__ counts, int E) {
    int e = blockIdx.x * 256 + threadIdx.x;
    if (e < E) atomicAdd(&counts[Li[e].x], 1);
}

__global__ __launch_bounds__(256) void k_scan1(const int* __restrict__ counts,
                                               int* __restrict__ off,
                                               int* __restrict__ bsum, int n) {
    __shared__ int sa[256], sb[256];
    int tid = threadIdx.x, idx = blockIdx.x * 256 + tid;
    int v = (idx < n) ? counts[idx] : 0;
    sa[tid] = v; __syncthreads();
    int *src = sa, *dst = sb;
    for (int ofs = 1; ofs < 256; ofs <<= 1) {
        int t = src[tid] + ((tid >= ofs) ? src[tid - ofs] : 0);
        dst[tid] = t; __syncthreads();
        int* tmp = src; src = dst; dst = tmp;
    }
    int inc = src[tid];
    if (idx < n) off[idx] = inc - v;           // block-local exclusive
    if (tid == 255) bsum[blockIdx.x] = inc;    // block total
}

__global__ __launch_bounds__(256) void k_scan2(int* __restrict__ bsum, int nb) {
    __shared__ int sa[256], sb[256];
    int tid = threadIdx.x;
    int v = (tid < nb) ? bsum[tid] : 0;
    sa[tid] = v; __syncthreads();
    int *src = sa, *dst = sb;
    for (int ofs = 1; ofs < 256; ofs <<= 1) {
        int t = src[tid] + ((tid >= ofs) ? src[tid - ofs] : 0);
        dst[tid] = t; __syncthreads();
        int* tmp = src; src = dst; dst = tmp;
    }
    if (tid < nb) bsum[tid] = src[tid] - v;    // exclusive block bases
}

__global__ __launch_bounds__(256) void k_scan3(int* __restrict__ off,
                                               const int* __restrict__ bsum,
                                               int n, int total) {
    int idx = blockIdx.x * 256 + threadIdx.x;
    if (idx < n) off[idx] += bsum[blockIdx.x];
    if (idx == 0) off[n] = total;
}

__global__ __launch_bounds__(256) void k_fill(const int2* __restrict__ Li,
                                              const int* __restrict__ row_off,
                                              int* __restrict__ cursor,
                                              int* __restrict__ csr_col, int E) {
    int e = blockIdx.x * 256 + threadIdx.x;
    if (e < E) {
        int2 rc = Li[e];
        int p = row_off[rc.x] + atomicAdd(&cursor[rc.x], 1);
        csr_col[p] = rc.y;
    }
}

// --- heavy kernel: one wave per (b, row); lane = feature dim ---
__global__ __launch_bounds__(256) void k_row(
    const int* __restrict__ row_off, const int* __restrict__ csr_col,
    const float* __restrict__ tf, const float4* __restrict__ node4,
    const float* __restrict__ er_arr, const float* __restrict__ sr_arr,
    const float* __restrict__ x_state, const float* __restrict__ self_act,
    const float* __restrict__ Xs,
    const float* __restrict__ sws_p, const float* __restrict__ swn_p,
    const float* __restrict__ iws_p, const float* __restrict__ iwn_p,
    float* __restrict__ out_state, float* __restrict__ out_infl, int N)
{
    int lane = threadIdx.x & 63;
    int r = blockIdx.x * 4 + (threadIdx.x >> 6);   // r in [0, B*N)
    int b = (r >= N) ? 1 : 0;
    int n = r - b * N;

    int beg = row_off[n];
    int end = row_off[n + 1];
    int cnt = end - beg;

    float er = er_arr[r], sr = sr_arr[r];
    const float4* nb = node4 + (size_t)b * N;
    const float* tfb = tf + (size_t)b * N * 64;

    float m = -3.0e38f, l = 0.f, acc = 0.f, sacc = 0.f;

    int c = (cnt > 0) ? csr_col[beg] : 0;   // software pipeline: index 1 ahead
    for (int k = 0; k < cnt; ++k) {
        float4 ns = nb[c];                              // {e_c, s_c, xs, gate}
        float tv = tfb[(size_t)c * 64 + lane];          // coalesced 256B gather
        int cn = (k + 1 < cnt) ? csr_col[beg + k + 1] : 0;

        // state message: leaky(s_r + s_c, 0.02) * x_state[col]
        float lgs = sr + ns.y;
        lgs = (lgs > 0.f) ? lgs : 0.02f * lgs;
        sacc = fmaf(lgs, ns.z, sacc);

        // attention logit: leaky(e_r + e_c, 0.2), online softmax
        float lg = er + ns.x;
        lg = (lg > 0.f) ? lg : 0.2f * lg;
        float nm = fmaxf(m, lg);
        float scl = __expf(m - nm);     // first iter: exp(-huge) = 0
        float pp  = __expf(lg - nm);
        l = fmaf(l, scl, pp);
        acc = fmaf(acc, scl, pp * (tv * ns.w));
        m = nm;
        c = cn;
    }

    float En = (cnt > 0) ? acc / l : 0.f;

    // output_influence = elu(iws * tf + iwn * E_neigh)
    float tsel = tfb[(size_t)n * 64 + lane];
    float oi = fmaf(iwn_p[0], En, iws_p[0] * tsel);
    out_infl[(size_t)r * 64 + lane] = elu_f(oi);

    if (lane == 0) {
        float Sn = sacc + self_act[n];
        float su = elu_f(fmaf(swn_p[0], Sn, sws_p[0] * x_state[r]));
        float X = Xs[r];
        out_state[r] = fmaf(su, 1.f - X, X);
    }
}

extern "C" void kernel_launch(void* const* d_in, const int* in_sizes, int n_in,
                              void* d_out, int out_size, void* d_ws, size_t ws_size,
                              hipStream_t stream) {
    const float* x_state  = (const float*)d_in[0];
    const float* x_infl   = (const float*)d_in[1];
    const int*   L_ind    = (const int*)d_in[2];
    // d_in[3] = L_values: unused by the reference
    const float* self_act = (const float*)d_in[4];
    const float* Xs       = (const float*)d_in[5];
    const float* Wg       = (const float*)d_in[6];
    const float* sbeta    = (const float*)d_in[7];
    const float* sws      = (const float*)d_in[8];
    const float* swn      = (const float*)d_in[9];
    const float* w1       = (const float*)d_in[10];
    const float* b1       = (const float*)d_in[11];
    const float* w2       = (const float*)d_in[12];
    const float* b2       = (const float*)d_in[13];
    const float* iatt     = (const float*)d_in[14];
    const float* iws      = (const float*)d_in[15];
    const float* iwn      = (const float*)d_in[16];

    const int N  = in_sizes[4];        // 50000
    const int BN = in_sizes[0];        // 100000
    const int E  = in_sizes[2] / 2;    // 800000

    // workspace carve (256B aligned chunks)
    char* p = (char*)d_ws;
    auto alloc = [&](size_t bytes) {
        void* q = (void*)p;
        p += (bytes + 255) & ~(size_t)255;
        return q;
    };
    float*  tf      = (float*) alloc((size_t)BN * 64 * 4);  // 25.6 MB
    float4* node4   = (float4*)alloc((size_t)BN * 16);      //  1.6 MB
    float*  er_arr  = (float*) alloc((size_t)BN * 4);
    float*  sr_arr  = (float*) alloc((size_t)BN * 4);
    int*    counts  = (int*)   alloc((size_t)N * 4);
    int*    cursor  = (int*)   alloc((size_t)N * 4);
    int*    row_off = (int*)   alloc((size_t)(N + 1) * 4);
    int*    bsum    = (int*)   alloc(1024 * 4);
    int*    csr_col = (int*)   alloc((size_t)E * 4);        //  3.2 MB

    hipMemsetAsync(counts, 0, (size_t)N * 4, stream);
    hipMemsetAsync(cursor, 0, (size_t)N * 4, stream);

    k_node<<<BN / 16, 256, 0, stream>>>(x_state, x_infl, Wg, sbeta,
                                        w1, b1, w2, b2, iatt,
                                        tf, node4, er_arr, sr_arr, BN);

    int ge = (E + 255) / 256;
    k_hist<<<ge, 256, 0, stream>>>((const int2*)L_ind, counts, E);

    int nb = (N + 255) / 256;
    k_scan1<<<nb, 256, 0, stream>>>(counts, row_off, bsum, N);
    k_scan2<<<1, 256, 0, stream>>>(bsum, nb);
    k_scan3<<<nb, 256, 0, stream>>>(row_off, bsum, N, E);

    k_fill<<<ge, 256, 0, stream>>>((const int2*)L_ind, row_off, cursor, csr_col, E);

    k_row<<<BN / 4, 256, 0, stream>>>(row_off, csr_col, tf, node4,
                                      er_arr, sr_arr, x_state, self_act, Xs,
                                      sws, swn, iws, iwn,
                                      (float*)d_out, (float*)d_out + BN, N);
}

// Round 2
// 329.290 us; speedup vs baseline: 1.1449x; 1.1449x over previous
//
#include <hip/hip_runtime.h>
#include <math.h>

// ---------------------------------------------------------------------------
// GraphConvolution: B=2, N=50000, D=64, E=800000, H=32
// R2: k_row restructured — phase 1 edge-parallel (lane k owns edge k of the
// row: one exp per edge instead of 64-redundant), phase 2 dim-parallel tf
// gather with shuffle-broadcast weights, unrolled x4 for MLP.
// CSR fill now decrements the (post-scan, still intact) histogram via
// atomicSub — drops the cursor buffer and its memset.
// ---------------------------------------------------------------------------

__device__ __forceinline__ float elu_f(float x) {
    return x > 0.f ? x : __expf(x) - 1.f;
}

__device__ __forceinline__ float4 wsum4(float4 v) {
#pragma unroll
    for (int m = 1; m < 64; m <<= 1) {
        v.x += __shfl_xor(v.x, m, 64);
        v.y += __shfl_xor(v.y, m, 64);
        v.z += __shfl_xor(v.z, m, 64);
        v.w += __shfl_xor(v.w, m, 64);
    }
    return v;
}

// --- per-node transform: 4 waves/block, 4 rows/wave ---
__global__ __launch_bounds__(256) void k_node(
    const float* __restrict__ x_state, const float* __restrict__ x_infl,
    const float* __restrict__ Wg, const float* __restrict__ sbeta,
    const float* __restrict__ w1, const float* __restrict__ b1,
    const float* __restrict__ w2, const float* __restrict__ b2,
    const float* __restrict__ iatt,
    float* __restrict__ tf, float4* __restrict__ node4,
    float* __restrict__ er_arr, float* __restrict__ sr_arr, int BN)
{
    __shared__ float Ws[4096];
    __shared__ float4 xT[4][64];
    __shared__ float mw1[32], mb1[32], mw2[32];
    __shared__ float mb2s;

    int tid = threadIdx.x;
#pragma unroll
    for (int i = tid; i < 4096; i += 256) Ws[i] = Wg[i];
    if (tid < 32) { mw1[tid] = w1[tid]; mb1[tid] = b1[tid]; mw2[tid] = w2[tid]; }
    if (tid == 0) mb2s = b2[0];

    int lane = tid & 63, w = tid >> 6;
    int rbase = blockIdx.x * 16 + w * 4;

    float xv0 = x_infl[(size_t)(rbase + 0) * 64 + lane];
    float xv1 = x_infl[(size_t)(rbase + 1) * 64 + lane];
    float xv2 = x_infl[(size_t)(rbase + 2) * 64 + lane];
    float xv3 = x_infl[(size_t)(rbase + 3) * 64 + lane];
    xT[w][lane] = make_float4(xv0, xv1, xv2, xv3);
    __syncthreads();

    float a0 = 0.f, a1 = 0.f, a2 = 0.f, a3 = 0.f;
#pragma unroll 16
    for (int k = 0; k < 64; ++k) {
        float wv = Ws[k * 64 + lane];
        float4 xk = xT[w][k];
        a0 = fmaf(xk.x, wv, a0);
        a1 = fmaf(xk.y, wv, a1);
        a2 = fmaf(xk.z, wv, a2);
        a3 = fmaf(xk.w, wv, a3);
    }
    tf[(size_t)(rbase + 0) * 64 + lane] = a0;
    tf[(size_t)(rbase + 1) * 64 + lane] = a1;
    tf[(size_t)(rbase + 2) * 64 + lane] = a2;
    tf[(size_t)(rbase + 3) * 64 + lane] = a3;

    float bsr = sbeta[lane], bsc = sbeta[64 + lane];
    float ber = iatt[lane],  bec = iatt[64 + lane];
    float4 d0 = wsum4(make_float4(a0 * bsr, a0 * bsc, a0 * ber, a0 * bec));
    float4 d1 = wsum4(make_float4(a1 * bsr, a1 * bsc, a1 * ber, a1 * bec));
    float4 d2 = wsum4(make_float4(a2 * bsr, a2 * bsc, a2 * ber, a2 * bec));
    float4 d3 = wsum4(make_float4(a3 * bsr, a3 * bsc, a3 * ber, a3 * bec));

    if (lane < 4) {
        float4 dd = (lane == 0) ? d0 : (lane == 1) ? d1 : (lane == 2) ? d2 : d3;
        int rr = rbase + lane;
        float xs = x_state[rr];
        float t = 0.f;
#pragma unroll
        for (int h = 0; h < 32; ++h) {
            float u = fmaf(xs, mw1[h], mb1[h]);
            u = elu_f(u);
            t = fmaf(u, mw2[h], t);
        }
        float gate = elu_f(t + mb2s);
        node4[rr] = make_float4(dd.w /*e_c*/, dd.y /*s_c*/, xs, gate);
        er_arr[rr] = dd.z;  // e_r
        sr_arr[rr] = dd.x;  // s_r
    }
}

// --- CSR build ---
__global__ __launch_bounds__(256) void k_hist(const int2* __restrict__ Li,
                                              int* __restrict__ counts, int E) {
    int e = blockIdx.x * 256 + threadIdx.x;
    if (e < E) atomicAdd(&counts[Li[e].x], 1);
}

__global__ __launch_bounds__(256) void k_scan1(const int* __restrict__ counts,
                                               int* __restrict__ off,
                                               int* __restrict__ bsum, int n) {
    __shared__ int sa[256], sb[256];
    int tid = threadIdx.x, idx = blockIdx.x * 256 + tid;
    int v = (idx < n) ? counts[idx] : 0;
    sa[tid] = v; __syncthreads();
    int *src = sa, *dst = sb;
    for (int ofs = 1; ofs < 256; ofs <<= 1) {
        int t = src[tid] + ((tid >= ofs) ? src[tid - ofs] : 0);
        dst[tid] = t; __syncthreads();
        int* tmp = src; src = dst; dst = tmp;
    }
    int inc = src[tid];
    if (idx < n) off[idx] = inc - v;
    if (tid == 255) bsum[blockIdx.x] = inc;
}

__global__ __launch_bounds__(256) void k_scan2(int* __restrict__ bsum, int nb) {
    __shared__ int sa[256], sb[256];
    int tid = threadIdx.x;
    int v = (tid < nb) ? bsum[tid] : 0;
    sa[tid] = v; __syncthreads();
    int *src = sa, *dst = sb;
    for (int ofs = 1; ofs < 256; ofs <<= 1) {
        int t = src[tid] + ((tid >= ofs) ? src[tid - ofs] : 0);
        dst[tid] = t; __syncthreads();
        int* tmp = src; src = dst; dst = tmp;
    }
    if (tid < nb) bsum[tid] = src[tid] - v;
}

__global__ __launch_bounds__(256) void k_scan3(int* __restrict__ off,
                                               const int* __restrict__ bsum,
                                               int n, int total) {
    int idx = blockIdx.x * 256 + threadIdx.x;
    if (idx < n) off[idx] += bsum[blockIdx.x];
    if (idx == 0) off[n] = total;
}

// fill by decrementing the (still-intact) histogram: no cursor buffer/memset.
// Within-row order is reversed vs edge order — segment sums are order-free.
__global__ __launch_bounds__(256) void k_fill(const int2* __restrict__ Li,
                                              const int* __restrict__ row_off,
                                              int* __restrict__ counts,
                                              int* __restrict__ csr_col, int E) {
    int e = blockIdx.x * 256 + threadIdx.x;
    if (e < E) {
        int2 rc = Li[e];
        int idx = atomicSub(&counts[rc.x], 1) - 1;
        csr_col[row_off[rc.x] + idx] = rc.y;
    }
}

// --- heavy kernel: one wave per (b, row) ---
// Phase 1: lane k owns edge k (chunk of 64): node4 gather, logits, one exp
//          per edge, wave-reduced max / sum(pp) / state-msg sum.
// Phase 2: dim-parallel tf gather; (c,w) broadcast via __shfl; unroll x4.
__global__ __launch_bounds__(256) void k_row(
    const int* __restrict__ row_off, const int* __restrict__ csr_col,
    const float* __restrict__ tf, const float4* __restrict__ node4,
    const float* __restrict__ er_arr, const float* __restrict__ sr_arr,
    const float* __restrict__ x_state, const float* __restrict__ self_act,
    const float* __restrict__ Xs,
    const float* __restrict__ sws_p, const float* __restrict__ swn_p,
    const float* __restrict__ iws_p, const float* __restrict__ iwn_p,
    float* __restrict__ out_state, float* __restrict__ out_infl, int N)
{
    int lane = threadIdx.x & 63;
    int r = blockIdx.x * 4 + (threadIdx.x >> 6);   // r in [0, B*N)
    int b = (r >= N) ? 1 : 0;
    int n = r - b * N;

    int beg = row_off[n];
    int end = row_off[n + 1];
    int cnt = end - beg;

    float er = er_arr[r], sr = sr_arr[r];
    const float4* nb = node4 + (size_t)b * N;
    const float* tfb = tf + (size_t)b * N * 64;

    float mrun = -3.0e38f, l = 0.f, sacc = 0.f, acc = 0.f;

    for (int q = beg; q < end; q += 64) {
        int cc = end - q; cc = (cc > 64) ? 64 : cc;
        bool act = lane < cc;

        int c = act ? csr_col[q + lane] : 0;
        float4 ns = nb[c];                       // {e_c, s_c, xs, gate} gather

        // state message (accumulate per-lane, reduce once at end)
        float lgs = sr + ns.y;
        lgs = (lgs > 0.f) ? lgs : 0.02f * lgs;
        sacc += act ? lgs * ns.z : 0.f;

        // attention logit
        float lg = act ? (er + ns.x) : -3.0e38f;
        lg = (lg > 0.f) ? lg : 0.2f * lg;        // -3e38*0.2 still ~ -inf
        float M = lg;
#pragma unroll
        for (int m = 1; m < 64; m <<= 1) M = fmaxf(M, __shfl_xor(M, m, 64));
        float nm = fmaxf(mrun, M);
        float scale = __expf(mrun - nm);         // first chunk: exp(-huge)=0
        float pp = __expf(lg - nm);              // inactive lanes -> 0
        float wgt = pp * ns.w;                   // fold gate in now
        float ps = pp;
#pragma unroll
        for (int m = 1; m < 64; m <<= 1) ps += __shfl_xor(ps, m, 64);
        l = fmaf(l, scale, ps);
        acc *= scale;
        mrun = nm;

        // Phase 2: gather tf rows, weight by broadcast wgt. Pad to x4 via
        // inactive lanes (c=0 valid, wgt=0 contributes nothing).
        int cc4 = (cc + 3) & ~3;
        for (int k = 0; k < cc4; k += 4) {
            int   c0 = __shfl(c, k + 0, 64), c1 = __shfl(c, k + 1, 64);
            int   c2 = __shfl(c, k + 2, 64), c3 = __shfl(c, k + 3, 64);
            float w0 = __shfl(wgt, k + 0, 64), w1v = __shfl(wgt, k + 1, 64);
            float w2v = __shfl(wgt, k + 2, 64), w3 = __shfl(wgt, k + 3, 64);
            float t0 = tfb[((unsigned)c0 << 6) + lane];
            float t1 = tfb[((unsigned)c1 << 6) + lane];
            float t2 = tfb[((unsigned)c2 << 6) + lane];
            float t3 = tfb[((unsigned)c3 << 6) + lane];
            acc = fmaf(w0, t0, acc);
            acc = fmaf(w1v, t1, acc);
            acc = fmaf(w2v, t2, acc);
            acc = fmaf(w3, t3, acc);
        }
    }

    float En = (cnt > 0) ? acc / l : 0.f;

    // output_influence = elu(iws * tf + iwn * E_neigh)
    float tsel = tfb[((unsigned)n << 6) + lane];
    float oi = fmaf(iwn_p[0], En, iws_p[0] * tsel);
    out_infl[(size_t)r * 64 + lane] = elu_f(oi);

    // state epilogue: reduce sacc across lanes
#pragma unroll
    for (int m = 1; m < 64; m <<= 1) sacc += __shfl_xor(sacc, m, 64);
    if (lane == 0) {
        float Sn = sacc + self_act[n];
        float su = elu_f(fmaf(swn_p[0], Sn, sws_p[0] * x_state[r]));
        float X = Xs[r];
        out_state[r] = fmaf(su, 1.f - X, X);
    }
}

extern "C" void kernel_launch(void* const* d_in, const int* in_sizes, int n_in,
                              void* d_out, int out_size, void* d_ws, size_t ws_size,
                              hipStream_t stream) {
    const float* x_state  = (const float*)d_in[0];
    const float* x_infl   = (const float*)d_in[1];
    const int*   L_ind    = (const int*)d_in[2];
    // d_in[3] = L_values: unused by the reference
    const float* self_act = (const float*)d_in[4];
    const float* Xs       = (const float*)d_in[5];
    const float* Wg       = (const float*)d_in[6];
    const float* sbeta    = (const float*)d_in[7];
    const float* sws      = (const float*)d_in[8];
    const float* swn      = (const float*)d_in[9];
    const float* w1       = (const float*)d_in[10];
    const float* b1       = (const float*)d_in[11];
    const float* w2       = (const float*)d_in[12];
    const float* b2       = (const float*)d_in[13];
    const float* iatt     = (const float*)d_in[14];
    const float* iws      = (const float*)d_in[15];
    const float* iwn      = (const float*)d_in[16];

    const int N  = in_sizes[4];        // 50000
    const int BN = in_sizes[0];        // 100000
    const int E  = in_sizes[2] / 2;    // 800000

    char* p = (char*)d_ws;
    auto alloc = [&](size_t bytes) {
        void* q = (void*)p;
        p += (bytes + 255) & ~(size_t)255;
        return q;
    };
    float*  tf      = (float*) alloc((size_t)BN * 64 * 4);  // 25.6 MB
    float4* node4   = (float4*)alloc((size_t)BN * 16);      //  1.6 MB
    float*  er_arr  = (float*) alloc((size_t)BN * 4);
    float*  sr_arr  = (float*) alloc((size_t)BN * 4);
    int*    counts  = (int*)   alloc((size_t)N * 4);
    int*    row_off = (int*)   alloc((size_t)(N + 1) * 4);
    int*    bsum    = (int*)   alloc(1024 * 4);
    int*    csr_col = (int*)   alloc((size_t)E * 4);        //  3.2 MB

    hipMemsetAsync(counts, 0, (size_t)N * 4, stream);

    k_node<<<BN / 16, 256, 0, stream>>>(x_state, x_infl, Wg, sbeta,
                                        w1, b1, w2, b2, iatt,
                                        tf, node4, er_arr, sr_arr, BN);

    int ge = (E + 255) / 256;
    k_hist<<<ge, 256, 0, stream>>>((const int2*)L_ind, counts, E);

    int nb = (N + 255) / 256;
    k_scan1<<<nb, 256, 0, stream>>>(counts, row_off, bsum, N);
    k_scan2<<<1, 256, 0, stream>>>(bsum, nb);
    k_scan3<<<nb, 256, 0, stream>>>(row_off, bsum, N, E);

    k_fill<<<ge, 256, 0, stream>>>((const int2*)L_ind, row_off, counts, csr_col, E);

    k_row<<<BN / 4, 256, 0, stream>>>(row_off, csr_col, tf, node4,
                                      er_arr, sr_arr, x_state, self_act, Xs,
                                      sws, swn, iws, iwn,
                                      (float*)d_out, (float*)d_out + BN, N);
}